// Round 1
// baseline (4653.116 us; speedup 1.0000x reference)
//
#include <hip/hip_runtime.h>
#include <float.h>

#define K_CODES 8192
#define DIM 64
#define D4 16            // DIM/4
#define ROWS 16          // rows per block
#define TCODES 128       // codes per outer iteration
#define OUTER (K_CODES / TCODES)   // 64

// ---------------------------------------------------------------------------
// Kernel 1: codebook squared norms -> ws
// ---------------------------------------------------------------------------
__global__ __launch_bounds__(256) void vq_norms(const float* __restrict__ cb,
                                                float* __restrict__ norms) {
    int k = blockIdx.x * 256 + threadIdx.x;
    const float4* c4 = (const float4*)(cb + (size_t)k * DIM);
    float4 acc = make_float4(0.f, 0.f, 0.f, 0.f);
#pragma unroll
    for (int i = 0; i < D4; ++i) {
        float4 v = c4[i];
        acc.x = fmaf(v.x, v.x, acc.x);
        acc.y = fmaf(v.y, v.y, acc.y);
        acc.z = fmaf(v.z, v.z, acc.z);
        acc.w = fmaf(v.w, v.w, acc.w);
    }
    norms[k] = (acc.x + acc.y) + (acc.z + acc.w);
}

// ---------------------------------------------------------------------------
// Kernel 2: fused argmin + gather + loss
// Block: 256 threads, 16 rows. Thread (cg = tid&31, rowgrp = tid>>5):
//   rows   r = rowgrp*2 + {0,1}
//   codes  k = t*128 + cg + 32*cc, cc in 0..3, t in 0..63 (ascending k per
//          thread -> strict '<' keeps first-min index like np.argmin)
// Discriminant g_k = ||c_k||^2 - 2 x.c_k (row-constant ||x||^2 dropped for
// precision: values ~1e-3, fp32 resolves gaps ~1e-9 << typical gap 2.7e-4).
// ---------------------------------------------------------------------------
__global__ __launch_bounds__(256, 4) void vq_main(
        const float* __restrict__ x, const float* __restrict__ cb,
        const float* __restrict__ norms,
        float* __restrict__ out_loss, float* __restrict__ out_q) {
    __shared__ float xs[ROWS * DIM];       // 4 KB, broadcast reads
    __shared__ float red_v[ROWS][32];
    __shared__ int   red_i[ROWS][32];
    __shared__ int   final_idx[ROWS];

    const int tid = threadIdx.x;
    const int cg = tid & 31;
    const int rowgrp = tid >> 5;           // 0..7, 2 rows each
    const size_t row0 = (size_t)blockIdx.x * ROWS;

    // stage x: 1024 floats = 256 float4, fully coalesced
    {
        const float4* src = (const float4*)(x + row0 * DIM);
        ((float4*)xs)[tid] = src[tid];
    }
    __syncthreads();

    const float4* cb4 = (const float4*)cb;
    const float4* xr0 = ((const float4*)xs) + (rowgrp * 2 + 0) * D4;
    const float4* xr1 = ((const float4*)xs) + (rowgrp * 2 + 1) * D4;

    float minv[2] = {FLT_MAX, FLT_MAX};
    int   mini[2] = {0, 0};

    for (int t = 0; t < OUTER; ++t) {
        const int kbase = t * TCODES + cg;
        float4 acc0[4], acc1[4];
#pragma unroll
        for (int cc = 0; cc < 4; ++cc) {
            acc0[cc] = make_float4(0.f, 0.f, 0.f, 0.f);
            acc1[cc] = make_float4(0.f, 0.f, 0.f, 0.f);
        }
#pragma unroll
        for (int d4 = 0; d4 < D4; ++d4) {
            float4 cv[4];
#pragma unroll
            for (int cc = 0; cc < 4; ++cc)
                cv[cc] = cb4[(size_t)(kbase + 32 * cc) * D4 + d4];
            float4 xv0 = xr0[d4];
            float4 xv1 = xr1[d4];
#pragma unroll
            for (int cc = 0; cc < 4; ++cc) {
                acc0[cc].x = fmaf(xv0.x, cv[cc].x, acc0[cc].x);
                acc0[cc].y = fmaf(xv0.y, cv[cc].y, acc0[cc].y);
                acc0[cc].z = fmaf(xv0.z, cv[cc].z, acc0[cc].z);
                acc0[cc].w = fmaf(xv0.w, cv[cc].w, acc0[cc].w);
                acc1[cc].x = fmaf(xv1.x, cv[cc].x, acc1[cc].x);
                acc1[cc].y = fmaf(xv1.y, cv[cc].y, acc1[cc].y);
                acc1[cc].z = fmaf(xv1.z, cv[cc].z, acc1[cc].z);
                acc1[cc].w = fmaf(xv1.w, cv[cc].w, acc1[cc].w);
            }
        }
#pragma unroll
        for (int cc = 0; cc < 4; ++cc) {
            const int k = kbase + 32 * cc;
            const float qn = norms[k];
            float d0 = (acc0[cc].x + acc0[cc].y) + (acc0[cc].z + acc0[cc].w);
            float d1 = (acc1[cc].x + acc1[cc].y) + (acc1[cc].z + acc1[cc].w);
            float g0 = fmaf(-2.f, d0, qn);
            float g1 = fmaf(-2.f, d1, qn);
            if (g0 < minv[0]) { minv[0] = g0; mini[0] = k; }
            if (g1 < minv[1]) { minv[1] = g1; mini[1] = k; }
        }
    }

    red_v[rowgrp * 2 + 0][cg] = minv[0];
    red_i[rowgrp * 2 + 0][cg] = mini[0];
    red_v[rowgrp * 2 + 1][cg] = minv[1];
    red_i[rowgrp * 2 + 1][cg] = mini[1];
    __syncthreads();

    if (tid < ROWS) {
        float bv = red_v[tid][0];
        int   bi = red_i[tid][0];
        for (int j = 1; j < 32; ++j) {
            float v = red_v[tid][j];
            int   i2 = red_i[tid][j];
            if (v < bv || (v == bv && i2 < bi)) { bv = v; bi = i2; }
        }
        final_idx[tid] = bi;
    }
    __syncthreads();

    // epilogue: 1024 elements, 4 per thread, coalesced
#pragma unroll
    for (int e = 0; e < 4; ++e) {
        int elem = e * 256 + tid;
        int r = elem >> 6;
        int d = elem & 63;
        float q  = cb[(size_t)final_idx[r] * DIM + d];
        float xv = xs[r * DIM + d];
        float diff = q - xv;
        size_t gidx = (row0 + r) * DIM + d;
        out_loss[gidx] = 1.25f * diff * diff;   // (q-x)^2 + 0.25*(q-x)^2
        out_q[gidx]    = q;                     // x + (q - x) == q
    }
}

extern "C" void kernel_launch(void* const* d_in, const int* in_sizes, int n_in,
                              void* d_out, int out_size, void* d_ws, size_t ws_size,
                              hipStream_t stream) {
    const float* x  = (const float*)d_in[0];   // [16,32,32,64] fp32
    const float* cb = (const float*)d_in[1];   // [8192,64] fp32
    float* norms = (float*)d_ws;               // 8192 floats scratch

    const int n_elems = in_sizes[0];           // 1048576
    float* out_loss = (float*)d_out;
    float* out_q    = out_loss + n_elems;

    vq_norms<<<K_CODES / 256, 256, 0, stream>>>(cb, norms);

    const int n_rows = n_elems / DIM;          // 16384
    vq_main<<<n_rows / ROWS, 256, 0, stream>>>(x, cb, norms, out_loss, out_q);
}

// Round 2
// 99.266 us; speedup vs baseline: 46.8752x; 46.8752x over previous
//
#include <hip/hip_runtime.h>
#include <float.h>

#define NROWS 16384
#define KC 8192
#define DIM 64
#define BM 128                       // rows per block
#define BN 128                       // codes per LDS tile
#define KSPLIT 4
#define CODES_PER_BLOCK (KC / KSPLIT)   // 2048
#define ITERS (CODES_PER_BLOCK / BN)    // 16

typedef __attribute__((ext_vector_type(8))) short bf16x8;   // 8 bf16 = 4 VGPRs
typedef __attribute__((ext_vector_type(4))) float f32x4;

// ws layout (bytes)
#define WS_CB16 0                          // 8192*64*2 = 1,048,576
#define WS_NORM 1048576                    // 8192*4    =    32,768
#define WS_PV   (WS_NORM + 32768)          // 16384*4*4 =   262,144
#define WS_PI   (WS_PV + 262144)           // 16384*4*4 =   262,144
// total ~1.6 MB

__device__ inline unsigned short f2bf(float f) {
    union { float f; unsigned u; } v; v.f = f;
    unsigned u = v.u;
    unsigned r = u + 0x7FFFu + ((u >> 16) & 1u);   // RNE (inputs are finite)
    return (unsigned short)(r >> 16);
}

// ---------------------------------------------------------------------------
// codebook squared norms (fp32)
// ---------------------------------------------------------------------------
__global__ __launch_bounds__(256) void vq_norms(const float* __restrict__ cb,
                                                float* __restrict__ norms) {
    int k = blockIdx.x * 256 + threadIdx.x;
    const float4* c4 = (const float4*)(cb + (size_t)k * DIM);
    float4 acc = make_float4(0.f, 0.f, 0.f, 0.f);
#pragma unroll
    for (int i = 0; i < DIM / 4; ++i) {
        float4 v = c4[i];
        acc.x = fmaf(v.x, v.x, acc.x);
        acc.y = fmaf(v.y, v.y, acc.y);
        acc.z = fmaf(v.z, v.z, acc.z);
        acc.w = fmaf(v.w, v.w, acc.w);
    }
    norms[k] = (acc.x + acc.y) + (acc.z + acc.w);
}

// ---------------------------------------------------------------------------
// codebook fp32 -> bf16 (row-major, linear; swizzle happens at staging time)
// ---------------------------------------------------------------------------
__global__ __launch_bounds__(256) void vq_cvt(const float* __restrict__ cb,
                                              unsigned short* __restrict__ cb16) {
    int t = blockIdx.x * 256 + threadIdx.x;        // 65536 threads, 8 elems each
    const float4* s = (const float4*)cb + (size_t)t * 2;
    float4 a = s[0], b = s[1];
    bf16x8 o;
    o[0] = (short)f2bf(a.x); o[1] = (short)f2bf(a.y);
    o[2] = (short)f2bf(a.z); o[3] = (short)f2bf(a.w);
    o[4] = (short)f2bf(b.x); o[5] = (short)f2bf(b.y);
    o[6] = (short)f2bf(b.z); o[7] = (short)f2bf(b.w);
    ((bf16x8*)cb16)[t] = o;
}

// ---------------------------------------------------------------------------
// main: 128x128-tile MFMA GEMM (A = -2x in regs, B = cb streamed via
// global_load_lds into XOR-swizzled double-buffered LDS) + fused argmin.
// Wave layout: 4 waves 2x2, each wave 64 rows x 64 codes (4x4 frags 16x16x32).
// g = ||c||^2 - 2 x.c  (row-constant ||x||^2 dropped; argmin-equivalent).
// ---------------------------------------------------------------------------
__global__ __launch_bounds__(256, 2) void vq_main(
        const float* __restrict__ x, const unsigned short* __restrict__ cb16,
        const float* __restrict__ cbnorm,
        float* __restrict__ pv, int* __restrict__ pi) {
    __shared__ __attribute__((aligned(16))) char smem[32768];   // x-stage / B dbuf / reduce
    __shared__ __attribute__((aligned(16))) float nrmLds[CODES_PER_BLOCK];

    const int tid = threadIdx.x;
    const int lane = tid & 63;
    const int wave = tid >> 6;             // 0..3
    const int waveM = wave >> 1, waveN = wave & 1;
    const int quad = lane >> 4, c15 = lane & 15;

    const int bx = blockIdx.x;
    const int rowTile = bx & (NROWS / BM - 1);   // 0..127
    const int split = bx >> 7;                   // 0..3
    const int splitBase = split * CODES_PER_BLOCK;
    const size_t rowBase = (size_t)rowTile * BM;

    // --- stage this split's code norms into LDS (8 KB) ---
    {
        const float4* s = (const float4*)(cbnorm + splitBase) + tid * 2;
        float4* d = (float4*)nrmLds + tid * 2;
        d[0] = s[0]; d[1] = s[1];
    }

    // --- stage x tile (fp32 -> bf16 of -2x), XOR-swizzled 16B chunks ---
    {
        bf16x8* xb = (bf16x8*)smem;
#pragma unroll
        for (int i = 0; i < 4; ++i) {
            int p = tid + 256 * i;             // dest chunk 0..1023
            int r = p >> 3, cp = p & 7;
            int c = cp ^ (r & 7);              // source chunk within row
            const float4* src = (const float4*)(x + (rowBase + r) * DIM + c * 8);
            float4 a = src[0], b = src[1];
            bf16x8 o;
            o[0] = (short)f2bf(-2.f * a.x); o[1] = (short)f2bf(-2.f * a.y);
            o[2] = (short)f2bf(-2.f * a.z); o[3] = (short)f2bf(-2.f * a.w);
            o[4] = (short)f2bf(-2.f * b.x); o[5] = (short)f2bf(-2.f * b.y);
            o[6] = (short)f2bf(-2.f * b.z); o[7] = (short)f2bf(-2.f * b.w);
            xb[p] = o;
        }
    }
    __syncthreads();

    // --- A fragments into registers (stay for whole kernel) ---
    // A-operand layout (16x16x32): lane holds row (lane&15), k = quad*8 + j
    bf16x8 afr[4][2];
    {
        const bf16x8* lds16 = (const bf16x8*)smem;
#pragma unroll
        for (int fm = 0; fm < 4; ++fm) {
            int r = waveM * 64 + fm * 16 + c15;
#pragma unroll
            for (int kk = 0; kk < 2; ++kk) {
                int cch = kk * 4 + quad;
                afr[fm][kk] = lds16[r * 8 + (cch ^ (r & 7))];
            }
        }
    }
    __syncthreads();   // smem free for B tiles

    // --- per-lane precomputed staging offsets (swizzle-inverse source) ---
    unsigned srcOff[4], ldsOff[4];
#pragma unroll
    for (int j = 0; j < 4; ++j) {
        int p = (wave * 4 + j) * 64 + lane;                    // dest chunk
        int q = (p & ~7) | ((p & 7) ^ ((p >> 3) & 7));         // source chunk
        srcOff[j] = (unsigned)q * 16u;
        ldsOff[j] = (unsigned)(wave * 4 + j) * 1024u;          // wave-uniform
    }

    const char* gcb = (const char*)cb16 + (size_t)splitBase * DIM * 2;

    f32x4 acc[4][4];
    float minv[4][4];
    int mini[4][4];
#pragma unroll
    for (int a = 0; a < 4; ++a)
#pragma unroll
        for (int b = 0; b < 4; ++b) { minv[a][b] = FLT_MAX; mini[a][b] = 0; }
    const f32x4 Z = {0.f, 0.f, 0.f, 0.f};

    // prefetch tile 0 into buffer 0
    {
        const char* g0 = gcb;
#pragma unroll
        for (int j = 0; j < 4; ++j)
            __builtin_amdgcn_global_load_lds(
                (const __attribute__((address_space(1))) void*)(g0 + srcOff[j]),
                (__attribute__((address_space(3))) void*)(smem + ldsOff[j]),
                16, 0, 0);
    }
    __syncthreads();

    for (int iter = 0; iter < ITERS; ++iter) {
        const int buf = iter & 1;
        if (iter + 1 < ITERS) {              // prefetch next tile (async)
            const char* gn = gcb + (size_t)(iter + 1) * BN * DIM * 2;
            char* lb = smem + (buf ^ 1) * 16384;
#pragma unroll
            for (int j = 0; j < 4; ++j)
                __builtin_amdgcn_global_load_lds(
                    (const __attribute__((address_space(1))) void*)(gn + srcOff[j]),
                    (__attribute__((address_space(3))) void*)(lb + ldsOff[j]),
                    16, 0, 0);
        }

        // B fragments (same per-lane pattern as A: lane holds code lane&15)
        const bf16x8* B16 = (const bf16x8*)(smem + buf * 16384);
        bf16x8 bfr[4][2];
#pragma unroll
        for (int fn = 0; fn < 4; ++fn) {
            int rB = waveN * 64 + fn * 16 + c15;
#pragma unroll
            for (int kk = 0; kk < 2; ++kk) {
                int cch = kk * 4 + quad;
                bfr[fn][kk] = B16[rB * 8 + (cch ^ (rB & 7))];
            }
        }

#pragma unroll
        for (int fm = 0; fm < 4; ++fm)
#pragma unroll
            for (int fn = 0; fn < 4; ++fn) {
                f32x4 t = __builtin_amdgcn_mfma_f32_16x16x32_bf16(
                    afr[fm][0], bfr[fn][0], Z, 0, 0, 0);
                acc[fm][fn] = __builtin_amdgcn_mfma_f32_16x16x32_bf16(
                    afr[fm][1], bfr[fn][1], t, 0, 0, 0);
            }

        // fused argmin epilogue. C/D layout: col=lane&15, row=quad*4+reg.
#pragma unroll
        for (int fn = 0; fn < 4; ++fn) {
            float nrm = nrmLds[iter * BN + waveN * 64 + fn * 16 + c15];
            int slot = iter * 4 + fn;        // packed (iter,fn), decode later
#pragma unroll
            for (int fm = 0; fm < 4; ++fm) {
#pragma unroll
                for (int rg = 0; rg < 4; ++rg) {
                    float g = acc[fm][fn][rg] + nrm;
                    bool lt = (g < minv[fm][rg]);       // strict: first idx wins
                    mini[fm][rg] = lt ? slot : mini[fm][rg];
                    minv[fm][rg] = fminf(minv[fm][rg], g);
                }
            }
        }
        __syncthreads();   // next tile staged (vmcnt drained) + buf reusable
    }

    // --- cross-lane / cross-wave reduction via LDS (reuse smem) ---
    float* redv = (float*)smem;              // [128][32]
    int* redi = (int*)(smem + 16384);        // [128][32]
#pragma unroll
    for (int fm = 0; fm < 4; ++fm)
#pragma unroll
        for (int rg = 0; rg < 4; ++rg) {
            int r = waveM * 64 + fm * 16 + quad * 4 + rg;
            int slot = waveN * 16 + c15;
            int pk = mini[fm][rg];
            redv[r * 32 + slot] = minv[fm][rg];
            redi[r * 32 + slot] = splitBase + waveN * 64 +
                                  (pk >> 2) * 128 + (pk & 3) * 16 + c15;
        }
    __syncthreads();
    if (tid < BM) {
        float bv = redv[tid * 32];
        int bi = redi[tid * 32];
        for (int j = 1; j < 32; ++j) {
            float v = redv[tid * 32 + j];
            int ii = redi[tid * 32 + j];
            if (v < bv || (v == bv && ii < bi)) { bv = v; bi = ii; }
        }
        pv[(rowBase + tid) * KSPLIT + split] = bv;
        pi[(rowBase + tid) * KSPLIT + split] = bi;
    }
}

// ---------------------------------------------------------------------------
// final: reduce KSPLIT partials per row, gather fp32 codebook, write outputs
// ---------------------------------------------------------------------------
__global__ __launch_bounds__(256) void vq_out(
        const float* __restrict__ x, const float* __restrict__ cb,
        const float* __restrict__ pv, const int* __restrict__ pi,
        float* __restrict__ out_loss, float* __restrict__ out_q) {
    __shared__ int idxs[16];
    const int tid = threadIdx.x;
    const size_t row0 = (size_t)blockIdx.x * 16;
    if (tid < 16) {
        size_t r = row0 + tid;
        float bv = pv[r * KSPLIT];
        int bi = pi[r * KSPLIT];
        for (int s = 1; s < KSPLIT; ++s) {
            float v = pv[r * KSPLIT + s];
            int ii = pi[r * KSPLIT + s];
            if (v < bv || (v == bv && ii < bi)) { bv = v; bi = ii; }
        }
        idxs[tid] = bi;
    }
    __syncthreads();
    const int r = tid >> 4;                 // 0..15
    const int d4 = tid & 15;                // float4 within row
    const int code = idxs[r];
    float4 q4 = ((const float4*)(cb + (size_t)code * DIM))[d4];
    float4 x4 = ((const float4*)(x + (row0 + r) * DIM))[d4];
    float4 l4;
    l4.x = 1.25f * (q4.x - x4.x) * (q4.x - x4.x);
    l4.y = 1.25f * (q4.y - x4.y) * (q4.y - x4.y);
    l4.z = 1.25f * (q4.z - x4.z) * (q4.z - x4.z);
    l4.w = 1.25f * (q4.w - x4.w) * (q4.w - x4.w);
    ((float4*)out_loss)[(row0 + r) * 16 + d4] = l4;
    ((float4*)out_q)[(row0 + r) * 16 + d4] = q4;
}

extern "C" void kernel_launch(void* const* d_in, const int* in_sizes, int n_in,
                              void* d_out, int out_size, void* d_ws, size_t ws_size,
                              hipStream_t stream) {
    const float* x = (const float*)d_in[0];    // [16,32,32,64] fp32
    const float* cb = (const float*)d_in[1];   // [8192,64] fp32
    char* ws = (char*)d_ws;
    unsigned short* cb16 = (unsigned short*)(ws + WS_CB16);
    float* norms = (float*)(ws + WS_NORM);
    float* pvb = (float*)(ws + WS_PV);
    int* pib = (int*)(ws + WS_PI);

    float* out_loss = (float*)d_out;
    float* out_q = out_loss + (size_t)NROWS * DIM;

    vq_norms<<<KC / 256, 256, 0, stream>>>(cb, norms);
    vq_cvt<<<(KC * DIM / 8) / 256, 256, 0, stream>>>(cb, cb16);
    vq_main<<<(NROWS / BM) * KSPLIT, 256, 0, stream>>>(x, cb16, norms, pvb, pib);
    vq_out<<<NROWS / 16, 256, 0, stream>>>(x, cb, pvb, pib, out_loss, out_q);
}

// Round 3
// 98.376 us; speedup vs baseline: 47.2993x; 1.0090x over previous
//
#include <hip/hip_runtime.h>
#include <float.h>

#define NROWS 16384
#define KC 8192
#define DIM 64
#define BM 128
#define KSPLIT 16
#define CPB (KC / KSPLIT)          // 512 codes per block (64 KB bf16 in LDS)
#define NSUB (CPB / 128)           // 4 subtiles of 128 codes

typedef __attribute__((ext_vector_type(8))) short bf16x8;   // 8 bf16 = 4 VGPRs
typedef __attribute__((ext_vector_type(4))) float f32x4;

// ws layout (bytes): cb16 1 MB | norms 32 KB | gmin 64 KB  (~1.14 MB total)
#define WS_CB16 0
#define WS_NORM (KC * DIM * 2)
#define WS_GMIN (WS_NORM + KC * 4)

__device__ inline unsigned short f2bf(float f) {
    union { float f; unsigned u; } v; v.f = f;
    unsigned u = v.u;
    unsigned r = u + 0x7FFFu + ((u >> 16) & 1u);   // RNE, finite inputs
    return (unsigned short)(r >> 16);
}
__device__ inline unsigned asu(float f) { union { float f; unsigned u; } v; v.f = f; return v.u; }
__device__ inline float asf(unsigned u) { union { float f; unsigned u; } v; v.u = u; return v.f; }

// ---------------------------------------------------------------------------
// prep: codebook fp32 -> bf16 (linear), fp32 norms, init gmin = 0xFFFFFFFF.
// 4 threads per code row; coalesced 64 B per thread.
// ---------------------------------------------------------------------------
__global__ __launch_bounds__(256) void vq_prep(const float* __restrict__ cb,
        unsigned short* __restrict__ cb16, float* __restrict__ norms,
        unsigned* __restrict__ gmin) {
    const int g = blockIdx.x * 256 + threadIdx.x;    // 32768 threads
    const int c = g >> 2, q = g & 3;
    const float4* s = (const float4*)cb + (size_t)c * 16 + q * 4;
    float4 a = s[0], b = s[1], d = s[2], e = s[3];
    float p = 0.f;
    p = fmaf(a.x, a.x, p); p = fmaf(a.y, a.y, p); p = fmaf(a.z, a.z, p); p = fmaf(a.w, a.w, p);
    p = fmaf(b.x, b.x, p); p = fmaf(b.y, b.y, p); p = fmaf(b.z, b.z, p); p = fmaf(b.w, b.w, p);
    p = fmaf(d.x, d.x, p); p = fmaf(d.y, d.y, p); p = fmaf(d.z, d.z, p); p = fmaf(d.w, d.w, p);
    p = fmaf(e.x, e.x, p); p = fmaf(e.y, e.y, p); p = fmaf(e.z, e.z, p); p = fmaf(e.w, e.w, p);
    bf16x8 o0, o1;
    o0[0] = (short)f2bf(a.x); o0[1] = (short)f2bf(a.y); o0[2] = (short)f2bf(a.z); o0[3] = (short)f2bf(a.w);
    o0[4] = (short)f2bf(b.x); o0[5] = (short)f2bf(b.y); o0[6] = (short)f2bf(b.z); o0[7] = (short)f2bf(b.w);
    o1[0] = (short)f2bf(d.x); o1[1] = (short)f2bf(d.y); o1[2] = (short)f2bf(d.z); o1[3] = (short)f2bf(d.w);
    o1[4] = (short)f2bf(e.x); o1[5] = (short)f2bf(e.y); o1[6] = (short)f2bf(e.z); o1[7] = (short)f2bf(e.w);
    bf16x8* dst = (bf16x8*)cb16 + (size_t)c * 8 + q * 2;
    dst[0] = o0; dst[1] = o1;
    p += __shfl_xor(p, 1);          // 4 consecutive lanes share a code row
    p += __shfl_xor(p, 2);
    if (q == 0) norms[c] = p;
    if (g < NROWS) gmin[g] = 0xFFFFFFFFu;
}

// ---------------------------------------------------------------------------
// main: persistent-LDS codebook split (512 codes, 64 KB), barrier-free inner
// loop. A = -2x bf16 in registers (direct global load). g = ||c||^2 - 2 x.c
// computed by MFMA with C-init = ||c||^2. Argmin via packed keys:
//   key = (bits(g) & ~0x1FFF) | code   (13-bit code in low mantissa bits)
// -> v_and_or + v_min_f32 per value. shfl butterfly + device atomicMin.
// ---------------------------------------------------------------------------
__global__ __launch_bounds__(256, 2) void vq_main(
        const float* __restrict__ x, const unsigned short* __restrict__ cb16,
        const float* __restrict__ cbnorm, unsigned* __restrict__ gmin) {
    __shared__ __attribute__((aligned(16))) char smem[65536];   // 512 codes bf16

    const int tid = threadIdx.x;
    const int lane = tid & 63;
    const int wave = tid >> 6;
    const int waveM = wave >> 1, waveN = wave & 1;
    const int quad = lane >> 4, c15 = lane & 15;

    const int rowTile = blockIdx.x & 127;
    const int split = blockIdx.x >> 7;
    const int splitBase = split * CPB;
    const size_t rowBase = (size_t)rowTile * BM;

    // --- issue codebook split staging: 4096 x 16B chunks, XOR-swizzled dest
    const char* gcb = (const char*)cb16 + (size_t)splitBase * DIM * 2;
#pragma unroll
    for (int j = 0; j < 16; ++j) {
        int p = j * 256 + tid;                                  // dest chunk
        int q = (p & ~7) | ((p & 7) ^ ((p >> 3) & 7));          // src chunk
        __builtin_amdgcn_global_load_lds(
            (const __attribute__((address_space(1))) void*)(gcb + (size_t)q * 16),
            (__attribute__((address_space(3))) void*)(smem + (size_t)(j * 256 + wave * 64) * 16),
            16, 0, 0);
    }

    // --- A fragments straight from global (overlaps the DMA above)
    bf16x8 afr[4][2];
#pragma unroll
    for (int fm = 0; fm < 4; ++fm) {
        const float* xr = x + (rowBase + waveM * 64 + fm * 16 + c15) * DIM;
#pragma unroll
        for (int kk = 0; kk < 2; ++kk) {
            const float4* s4 = (const float4*)(xr + kk * 32 + quad * 8);
            float4 a = s4[0], b = s4[1];
            bf16x8 o;
            o[0] = (short)f2bf(-2.f * a.x); o[1] = (short)f2bf(-2.f * a.y);
            o[2] = (short)f2bf(-2.f * a.z); o[3] = (short)f2bf(-2.f * a.w);
            o[4] = (short)f2bf(-2.f * b.x); o[5] = (short)f2bf(-2.f * b.y);
            o[6] = (short)f2bf(-2.f * b.z); o[7] = (short)f2bf(-2.f * b.w);
            afr[fm][kk] = o;
        }
    }

    // --- code norms for this lane's columns (16 scalars)
    float nrmv[NSUB][4];
#pragma unroll
    for (int st = 0; st < NSUB; ++st)
#pragma unroll
        for (int fn = 0; fn < 4; ++fn)
            nrmv[st][fn] = cbnorm[splitBase + st * 128 + waveN * 64 + fn * 16 + c15];

    __syncthreads();   // drains global_load_lds; LDS read-only from here on

    const unsigned laneSlotBase = (unsigned)(splitBase + waveN * 64 + c15);
    float key[4][4];
#pragma unroll
    for (int a = 0; a < 4; ++a)
#pragma unroll
        for (int b = 0; b < 4; ++b) key[a][b] = FLT_MAX;

    const bf16x8* B16 = (const bf16x8*)smem;

#pragma unroll
    for (int st = 0; st < NSUB; ++st) {
        bf16x8 bfr[4][2];
#pragma unroll
        for (int fn = 0; fn < 4; ++fn) {
            int rB = st * 128 + waveN * 64 + fn * 16 + c15;
#pragma unroll
            for (int kk = 0; kk < 2; ++kk) {
                int cch = kk * 4 + quad;
                bfr[fn][kk] = B16[rB * 8 + (cch ^ (rB & 7))];
            }
        }
#pragma unroll
        for (int fm = 0; fm < 4; ++fm)
#pragma unroll
            for (int fn = 0; fn < 4; ++fn) {
                f32x4 ci;
                ci[0] = nrmv[st][fn]; ci[1] = nrmv[st][fn];
                ci[2] = nrmv[st][fn]; ci[3] = nrmv[st][fn];
                f32x4 t = __builtin_amdgcn_mfma_f32_16x16x32_bf16(
                    afr[fm][0], bfr[fn][0], ci, 0, 0, 0);
                f32x4 g = __builtin_amdgcn_mfma_f32_16x16x32_bf16(
                    afr[fm][1], bfr[fn][1], t, 0, 0, 0);
                const unsigned slot = laneSlotBase + (unsigned)(st * 128 + fn * 16);
#pragma unroll
                for (int rg = 0; rg < 4; ++rg) {
                    unsigned u = (asu(g[rg]) & 0xFFFFE000u) | slot;
                    key[fm][rg] = fminf(key[fm][rg], asf(u));
                }
            }
    }

    // --- butterfly over the 16 code-lanes, then device-scope atomic merge
#pragma unroll
    for (int fm = 0; fm < 4; ++fm)
#pragma unroll
        for (int rg = 0; rg < 4; ++rg) {
            float k = key[fm][rg];
            k = fminf(k, __shfl_xor(k, 1));
            k = fminf(k, __shfl_xor(k, 2));
            k = fminf(k, __shfl_xor(k, 4));
            k = fminf(k, __shfl_xor(k, 8));
            key[fm][rg] = k;
        }
    if (c15 == 0) {
#pragma unroll
        for (int fm = 0; fm < 4; ++fm)
#pragma unroll
            for (int rg = 0; rg < 4; ++rg) {
                unsigned u = asu(key[fm][rg]);
                unsigned m = (u & 0x80000000u) ? ~u : (u | 0x80000000u);  // order-preserving map
                atomicMin(&gmin[rowBase + waveM * 64 + fm * 16 + quad * 4 + rg], m);
            }
    }
}

// ---------------------------------------------------------------------------
// out: decode winning code per row, gather fp32 codebook, write loss + q
// ---------------------------------------------------------------------------
__global__ __launch_bounds__(256) void vq_out(
        const float* __restrict__ x, const float* __restrict__ cb,
        const unsigned* __restrict__ gmin,
        float* __restrict__ out_loss, float* __restrict__ out_q) {
    __shared__ int idxs[16];
    const int tid = threadIdx.x;
    const size_t row0 = (size_t)blockIdx.x * 16;
    if (tid < 16) {
        unsigned u = gmin[row0 + tid];
        unsigned b = (u & 0x80000000u) ? (u ^ 0x80000000u) : ~u;  // unmap
        idxs[tid] = (int)(b & 8191u);
    }
    __syncthreads();
    const int r = tid >> 4;
    const int d4 = tid & 15;
    const int code = idxs[r];
    float4 q4 = ((const float4*)(cb + (size_t)code * DIM))[d4];
    float4 x4 = ((const float4*)(x + (row0 + r) * DIM))[d4];
    float4 l4;
    l4.x = 1.25f * (q4.x - x4.x) * (q4.x - x4.x);
    l4.y = 1.25f * (q4.y - x4.y) * (q4.y - x4.y);
    l4.z = 1.25f * (q4.z - x4.z) * (q4.z - x4.z);
    l4.w = 1.25f * (q4.w - x4.w) * (q4.w - x4.w);
    ((float4*)out_loss)[(row0 + r) * 16 + d4] = l4;
    ((float4*)out_q)[(row0 + r) * 16 + d4] = q4;
}

extern "C" void kernel_launch(void* const* d_in, const int* in_sizes, int n_in,
                              void* d_out, int out_size, void* d_ws, size_t ws_size,
                              hipStream_t stream) {
    const float* x = (const float*)d_in[0];    // [16,32,32,64] fp32
    const float* cb = (const float*)d_in[1];   // [8192,64] fp32
    char* ws = (char*)d_ws;
    unsigned short* cb16 = (unsigned short*)(ws + WS_CB16);
    float* norms = (float*)(ws + WS_NORM);
    unsigned* gmin = (unsigned*)(ws + WS_GMIN);

    float* out_loss = (float*)d_out;
    float* out_q = out_loss + (size_t)NROWS * DIM;

    vq_prep<<<128, 256, 0, stream>>>(cb, cb16, norms, gmin);
    vq_main<<<(NROWS / BM) * KSPLIT, 256, 0, stream>>>(x, cb16, norms, gmin);
    vq_out<<<NROWS / 16, 256, 0, stream>>>(x, cb, gmin, out_loss, out_q);
}